// Round 4
// baseline (1075.222 us; speedup 1.0000x reference)
//
#include <hip/hip_runtime.h>

// GRU fused, round 10: MFMA batch-16 restructure (round-9 resubmit; infra
// failed — no counters, push path showed 600s+ stalls in round 2's timing).
// Defensive delta vs round 9: dropped amdgpu_waves_per_eu(1,1) (no benefit
// at 64-thread blocks; removes one exotic attribute from suspicion).
//
// Design recap: rounds 6/8 showed the recurrence is latency-bound on VALU
// (~70-100 cyc/batch-step for 6.9K MACs). One wave owns 16 batches;
// G[144x16] = [W_hh|W_ih|b]*[h;x;1] via mfma_f32_16x16x32_f16 (f16 in,
// f32 acc - same numerics as fdot2 path). r/z/n/h tiles share the C/D
// (lane,reg) mapping -> activation+combine elementwise in-register; only
// shuffle is h C/D->B-frag repack (15 ds_bpermute + selects). FC = 2 more
// MFMAs on the fresh frags. 128 single-wave blocks, no barriers.

typedef _Float16 f16x8 __attribute__((ext_vector_type(8)));
typedef float f32x4 __attribute__((ext_vector_type(4)));
typedef __fp16 h2_t __attribute__((ext_vector_type(2)));

namespace {

constexpr int T  = 1024;
constexpr int DM = 6;
constexpr int H  = 48;
constexpr int NB = 16;    // batches per wave

__device__ __forceinline__ float fexp2(float x) { return __builtin_amdgcn_exp2f(x); }
__device__ __forceinline__ float frcp(float x) { return __builtin_amdgcn_rcpf(x); }
__device__ __forceinline__ float sigmoid_f(float x) {
  return frcp(1.0f + fexp2(-1.44269504088896340736f * x));
}
__device__ __forceinline__ float tanh_f(float x) {
  float e = fexp2(2.88539008177792681472f * x);
  return 1.0f - 2.0f * frcp(e + 1.0f);
}
__device__ __forceinline__ unsigned pk(float a, float b) {   // RTZ pack (weights/x)
  union { h2_t h; unsigned u; } r; r.h = __builtin_amdgcn_cvt_pkrtz(a, b); return r.u;
}
__device__ __forceinline__ unsigned pk_rtn(float a, float b) {  // RTN pack (h state)
  union { __fp16 h[2]; unsigned u; } r; r.h[0] = (__fp16)a; r.h[1] = (__fp16)b; return r.u;
}

union F8 { unsigned u[4]; f16x8 v; };

// fused K-column value: kk<48 -> W row; 48..53 -> W_ih row (x slot);
// 54 -> bias (vs constant 1.0 in B); else 0.
__device__ __forceinline__ float kv48(const float* Wrow, const float* IHrow,
                                      float bias, int kk) {
  if (kk < 48) return Wrow ? Wrow[kk] : 0.0f;
  if (kk < 54) return IHrow ? IHrow[kk - 48] : 0.0f;
  if (kk == 54) return bias;
  return 0.0f;
}

__global__ __launch_bounds__(64)
void gru_mfma(
    const float* __restrict__ x, const float* __restrict__ W_ih,
    const float* __restrict__ W_hh, const float* __restrict__ b_ih,
    const float* __restrict__ b_hh, const float* __restrict__ fc_w,
    const float* __restrict__ fc_b, float* __restrict__ y) {

  const int l = threadIdx.x & 63;
  const int c = l & 15;          // batch col (B/C/D) and M-row (A)
  const int q = l >> 4;          // lane quad: k-group / C-row group
  const size_t bb = (size_t)blockIdx.x * NB;

  // ---- loop-invariant A fragments (f16), lane: row=c, k=8q+i (+kbase) ----
  F8 aRZ0[6], aRZ1[6], aGH0[3], aGH1[3], aGI[3], aFC0, aFC1;
#pragma unroll
  for (int tt = 0; tt < 6; ++tt) {                 // r rows 0-47, z rows 48-95
    const int grow = tt * 16 + c;
    const float* wr = W_hh + grow * H;
    const float* ir = W_ih + grow * DM;
    const float bs = b_ih[grow] + b_hh[grow];
#pragma unroll
    for (int w = 0; w < 4; ++w) {
      aRZ0[tt].u[w] = pk(wr[8 * q + 2 * w], wr[8 * q + 2 * w + 1]);
      aRZ1[tt].u[w] = pk(kv48(wr, ir, bs, 32 + 8 * q + 2 * w),
                         kv48(wr, ir, bs, 32 + 8 * q + 2 * w + 1));
    }
  }
#pragma unroll
  for (int tt = 0; tt < 3; ++tt) {                 // n rows 96-143
    const int grow = 96 + tt * 16 + c;
    const float* wr = W_hh + grow * H;
    const float* ir = W_ih + grow * DM;
    const float bh = b_hh[grow], bi = b_ih[grow];
#pragma unroll
    for (int w = 0; w < 4; ++w) {
      aGH0[tt].u[w] = pk(wr[8 * q + 2 * w], wr[8 * q + 2 * w + 1]);
      aGH1[tt].u[w] = pk(kv48(wr, nullptr, bh, 32 + 8 * q + 2 * w),
                         kv48(wr, nullptr, bh, 32 + 8 * q + 2 * w + 1));
      const int k0 = 8 * q + 2 * w, k1 = k0 + 1;
      auto gv = [&](int k) -> float {
        return k < 6 ? ir[k] : (k == 6 ? bi : 0.0f);
      };
      aGI[tt].u[w] = (q == 0) ? pk(gv(k0), gv(k1)) : 0u;   // gi: x at k0-5, bias k6
    }
  }
  {
    const bool vr = (c < DM);                      // FC rows 0-5 valid
    const float* wr = vr ? (fc_w + c * H) : nullptr;
    const float fb = vr ? fc_b[c] : 0.0f;
#pragma unroll
    for (int w = 0; w < 4; ++w) {
      aFC0.u[w] = wr ? pk(wr[8 * q + 2 * w], wr[8 * q + 2 * w + 1]) : 0u;
      aFC1.u[w] = pk(kv48(wr, nullptr, fb, 32 + 8 * q + 2 * w),
                     kv48(wr, nullptr, fb, 32 + 8 * q + 2 * w + 1));
    }
  }

  // ---- state ----
  float hf[3][4];                 // h f32, C/D layout: [tile][j], row=16t+4q+j, col=c
  unsigned hp[3][2];              // h packed f16 pairs
#pragma unroll
  for (int tt = 0; tt < 3; ++tt) {
    hp[tt][0] = 0u; hp[tt][1] = 0u;
#pragma unroll
    for (int j = 0; j < 4; ++j) hf[tt][j] = 0.0f;
  }

  const int addrA = 4 * (c + 32 * (q & 1));   // bpermute src: q0/q2->lane c, q1/q3->c+32
  const int addrB = addrA + 64;               // +16 lanes
  const int addrX = 4 * (32 + c);             // x lives in lane 32+c (q2)
  const unsigned c10 = 0x00003C00u;           // f16 pair (1.0, 0.0)

  const float* xp = x + (bb + c) * (size_t)(T * DM);
  float* yp = y + (bb + c) * (size_t)(T * DM);

  float2 nx0 = {0, 0}, nx1 = {0, 0}, nx2 = {0, 0};
  if (q == 2) {                                // x[0]
    const float2* p = (const float2*)xp;
    nx0 = p[0]; nx1 = p[1]; nx2 = p[2];
  }
  unsigned xw0 = pk(nx0.x, nx0.y), xw1 = pk(nx1.x, nx1.y), xw2 = pk(nx2.x, nx2.y);

  unsigned b0u[4], b1u[4], xbu[4];

  // Rebuild B-frags from hp (C/D layout) + xw. B chunk0 = h rows 0-31,
  // chunk1 = h rows 32-47 | x (k48-53) | 1.0 (k54) | 0; xb = x | bias-one.
#define REBUILD() do {                                                   \
    int A00 = __builtin_amdgcn_ds_bpermute(addrA, (int)hp[0][0]);        \
    int A01 = __builtin_amdgcn_ds_bpermute(addrA, (int)hp[0][1]);        \
    int A10 = __builtin_amdgcn_ds_bpermute(addrA, (int)hp[1][0]);        \
    int A11 = __builtin_amdgcn_ds_bpermute(addrA, (int)hp[1][1]);        \
    int A20 = __builtin_amdgcn_ds_bpermute(addrA, (int)hp[2][0]);        \
    int A21 = __builtin_amdgcn_ds_bpermute(addrA, (int)hp[2][1]);        \
    int B00 = __builtin_amdgcn_ds_bpermute(addrB, (int)hp[0][0]);        \
    int B01 = __builtin_amdgcn_ds_bpermute(addrB, (int)hp[0][1]);        \
    int B10 = __builtin_amdgcn_ds_bpermute(addrB, (int)hp[1][0]);        \
    int B11 = __builtin_amdgcn_ds_bpermute(addrB, (int)hp[1][1]);        \
    int B20 = __builtin_amdgcn_ds_bpermute(addrB, (int)hp[2][0]);        \
    int B21 = __builtin_amdgcn_ds_bpermute(addrB, (int)hp[2][1]);        \
    int GX0 = __builtin_amdgcn_ds_bpermute(addrX, (int)xw0);             \
    int GX1 = __builtin_amdgcn_ds_bpermute(addrX, (int)xw1);             \
    int GX2 = __builtin_amdgcn_ds_bpermute(addrX, (int)xw2);             \
    const bool pq2 = (q & 2) != 0, phi = (q >= 2), pq3 = (q == 3);       \
    const bool pq0 = (q == 0);                                           \
    b0u[0] = (unsigned)(pq2 ? A10 : A00);                                \
    b0u[1] = (unsigned)(pq2 ? A11 : A01);                                \
    b0u[2] = (unsigned)(pq2 ? B10 : B00);                                \
    b0u[3] = (unsigned)(pq2 ? B11 : B01);                                \
    b1u[0] = phi ? (pq3 ? 0u : xw0) : (unsigned)A20;                     \
    b1u[1] = phi ? (pq3 ? 0u : xw1) : (unsigned)A21;                     \
    b1u[2] = phi ? (pq3 ? 0u : xw2) : (unsigned)B20;                     \
    b1u[3] = phi ? (pq3 ? 0u : c10) : (unsigned)B21;                     \
    xbu[0] = pq0 ? (unsigned)GX0 : 0u;                                   \
    xbu[1] = pq0 ? (unsigned)GX1 : 0u;                                   \
    xbu[2] = pq0 ? (unsigned)GX2 : 0u;                                   \
    xbu[3] = pq0 ? c10 : 0u;                                             \
  } while (0)

  REBUILD();                                   // frags for t=0 (h=0, x[0])

  if (q == 2) {                                // prefetch x[1]
    const float2* p = (const float2*)(xp + DM);
    nx0 = p[0]; nx1 = p[1]; nx2 = p[2];
  }

  const f32x4 z4 = {0.0f, 0.0f, 0.0f, 0.0f};

#pragma unroll 1
  for (int t = 0; t < T; ++t) {
    F8 B0, B1, XB;
#pragma unroll
    for (int w = 0; w < 4; ++w) { B0.u[w] = b0u[w]; B1.u[w] = b1u[w]; XB.u[w] = xbu[w]; }

    // gates: 21 mfma, all independent given frags
    f32x4 aR[3], aZ[3], aGHv[3], aGIv[3];
#pragma unroll
    for (int tt = 0; tt < 3; ++tt) {
      aR[tt]  = __builtin_amdgcn_mfma_f32_16x16x32_f16(aRZ0[tt].v, B0.v, z4, 0, 0, 0);
      aR[tt]  = __builtin_amdgcn_mfma_f32_16x16x32_f16(aRZ1[tt].v, B1.v, aR[tt], 0, 0, 0);
      aZ[tt]  = __builtin_amdgcn_mfma_f32_16x16x32_f16(aRZ0[tt + 3].v, B0.v, z4, 0, 0, 0);
      aZ[tt]  = __builtin_amdgcn_mfma_f32_16x16x32_f16(aRZ1[tt + 3].v, B1.v, aZ[tt], 0, 0, 0);
      aGHv[tt] = __builtin_amdgcn_mfma_f32_16x16x32_f16(aGH0[tt].v, B0.v, z4, 0, 0, 0);
      aGHv[tt] = __builtin_amdgcn_mfma_f32_16x16x32_f16(aGH1[tt].v, B1.v, aGHv[tt], 0, 0, 0);
      aGIv[tt] = __builtin_amdgcn_mfma_f32_16x16x32_f16(aGI[tt].v, XB.v, z4, 0, 0, 0);
    }

    // commit x[t+1] (loaded last iter), issue x[t+2] loads
    xw0 = pk(nx0.x, nx0.y); xw1 = pk(nx1.x, nx1.y); xw2 = pk(nx2.x, nx2.y);
    if (q == 2) {
      const int tn = (t + 2 < T) ? (t + 2) : (T - 1);
      const float2* p = (const float2*)(xp + tn * DM);
      nx0 = p[0]; nx1 = p[1]; nx2 = p[2];
    }

    // activations + combine: r/z/n/h tiles share (lane,j) mapping
#pragma unroll
    for (int tt = 0; tt < 3; ++tt) {
#pragma unroll
      for (int j = 0; j < 4; ++j) {
        const float r_ = sigmoid_f(aR[tt][j]);
        const float zz = sigmoid_f(aZ[tt][j]);
        const float n_ = tanh_f(fmaf(r_, aGHv[tt][j], aGIv[tt][j]));
        hf[tt][j] = fmaf(zz, hf[tt][j] - n_, n_);   // n + z*(h-n)
      }
      hp[tt][0] = pk_rtn(hf[tt][0], hf[tt][1]);
      hp[tt][1] = pk_rtn(hf[tt][2], hf[tt][3]);
    }

    REBUILD();                                 // frags for t+1 (h[t], x[t+1])

    // FC on fresh frags -> y[t]; x-slots hit zero FC weights, k54 adds fc_b
#pragma unroll
    for (int w = 0; w < 4; ++w) { B0.u[w] = b0u[w]; B1.u[w] = b1u[w]; }
    f32x4 yacc = __builtin_amdgcn_mfma_f32_16x16x32_f16(aFC0.v, B0.v, z4, 0, 0, 0);
    yacc = __builtin_amdgcn_mfma_f32_16x16x32_f16(aFC1.v, B1.v, yacc, 0, 0, 0);

    if (q == 0) {                              // rows 0-3 -> y[b][t][0..3]
      float2 s0 = {yacc[0], yacc[1]}, s1 = {yacc[2], yacc[3]};
      *(float2*)(yp + t * DM) = s0;
      *(float2*)(yp + t * DM + 2) = s1;
    } else if (q == 1) {                       // rows 4-5 -> y[b][t][4..5]
      float2 s = {yacc[0], yacc[1]};
      *(float2*)(yp + t * DM + 4) = s;
    }
  }
#undef REBUILD
}

}  // namespace

extern "C" void kernel_launch(void* const* d_in, const int* in_sizes, int n_in,
                              void* d_out, int out_size, void* d_ws, size_t ws_size,
                              hipStream_t stream) {
  const float* x    = (const float*)d_in[0];
  const float* W_ih = (const float*)d_in[1];
  const float* W_hh = (const float*)d_in[2];
  const float* b_ih = (const float*)d_in[3];
  const float* b_hh = (const float*)d_in[4];
  const float* fc_w = (const float*)d_in[5];
  const float* fc_b = (const float*)d_in[6];
  float* y = (float*)d_out;

  constexpr int B = 2048;
  gru_mfma<<<B / NB, 64, 0, stream>>>(x, W_ih, W_hh, b_ih, b_hh, fc_w, fc_b, y);
}

// Round 5
// 677.075 us; speedup vs baseline: 1.5880x; 1.5880x over previous
//
#include <hip/hip_runtime.h>

// GRU fused, round 11: 3-wave row-split MFMA.
// Round 10 (validated correct, 1023us): one wave owned all 48 gate rows ->
// 12 activation-sets/lane (~540 cyc TRANS-heavy serial issue) + 15-bpermute
// REBUILD (~600-800 cyc) = 2400 cyc/step, fully latency-exposed.
// Split rows across 3 waves (16-row tile each): 7 MFMAs/wave, 4 act
// sets/lane, h exchanged via LDS (1 ds_write_b64 + 2 ds_read_b128, one
// lgkm-only barrier per step; x prefetch loads stay in flight across it).
// Fragment k-mapping identical to the validated round-10 kernel.

typedef _Float16 f16x8 __attribute__((ext_vector_type(8)));
typedef float f32x4 __attribute__((ext_vector_type(4)));
typedef __fp16 h2_t __attribute__((ext_vector_type(2)));

namespace {

constexpr int T  = 1024;
constexpr int DM = 6;
constexpr int H  = 48;
constexpr int NB = 16;     // batches per block
constexpr int CSTR = 28;   // dwords per column in hbuf: 16B-aligned b128 reads,
                           // 28c mod 32 has period 8 -> max 2-way read conflict (free)

__device__ __forceinline__ float fexp2(float x) { return __builtin_amdgcn_exp2f(x); }
__device__ __forceinline__ float frcp(float x) { return __builtin_amdgcn_rcpf(x); }
__device__ __forceinline__ float sigmoid_f(float x) {
  return frcp(1.0f + fexp2(-1.44269504088896340736f * x));
}
__device__ __forceinline__ float tanh_f(float x) {
  float e = fexp2(2.88539008177792681472f * x);
  return 1.0f - 2.0f * frcp(e + 1.0f);
}
__device__ __forceinline__ unsigned pk(float a, float b) {   // RTZ (weights/x)
  union { h2_t h; unsigned u; } r; r.h = __builtin_amdgcn_cvt_pkrtz(a, b); return r.u;
}
__device__ __forceinline__ unsigned pk_rtn(float a, float b) {  // RTN (h state)
  union { __fp16 h[2]; unsigned u; } r; r.h[0] = (__fp16)a; r.h[1] = (__fp16)b; return r.u;
}

union F8 { unsigned u[4]; f16x8 v; };

// fused K-column: kk<48 -> W_hh row; 48..53 -> W_ih row (x slots); 54 -> bias.
__device__ __forceinline__ float kv48(const float* Wrow, const float* IHrow,
                                      float bias, int kk) {
  if (kk < 48) return Wrow ? Wrow[kk] : 0.0f;
  if (kk < 54) return IHrow ? IHrow[kk - 48] : 0.0f;
  if (kk == 54) return bias;
  return 0.0f;
}

// Barrier draining LDS only: x prefetch (vmcnt) stays in flight.
__device__ __forceinline__ void bar_lgkm() {
  asm volatile("s_waitcnt lgkmcnt(0)\n\ts_barrier" ::: "memory");
}

__global__ __launch_bounds__(192)
void gru_mfma3(
    const float* __restrict__ x, const float* __restrict__ W_ih,
    const float* __restrict__ W_hh, const float* __restrict__ b_ih,
    const float* __restrict__ b_hh, const float* __restrict__ fc_w,
    const float* __restrict__ fc_b, float* __restrict__ y) {

  // h store: [buf][col*CSTR + pair], pair p of col c = h rows (2p, 2p+1),
  // even row in low f16 (matches A-frag pk(w[k],w[k+1]) convention).
  __shared__ unsigned hbuf[2][16 * CSTR];

  const int tid = threadIdx.x;
  const int wid = tid >> 6;        // row tile 0..2 (rows 16*wid..16*wid+15 of each gate)
  const int l   = tid & 63;
  const int c   = l & 15;          // batch col (B/C/D) and M-row (A)
  const int q   = l >> 4;          // lane quad
  const size_t bb = (size_t)blockIdx.x * NB;

  // ---- loop-invariant A fragments for this wave's row tile ----
  F8 aR0, aR1, aZ0, aZ1, aG0, aG1, aGI;
  {
    const int rrow = wid * 16 + c;                 // r rows 0..47
    const int zrow = 48 + wid * 16 + c;            // z rows 48..95
    const int nrow = 96 + wid * 16 + c;            // n rows 96..143
    const float* wr = W_hh + rrow * H; const float* ir  = W_ih + rrow * DM;
    const float* wz = W_hh + zrow * H; const float* iz  = W_ih + zrow * DM;
    const float* wn = W_hh + nrow * H; const float* in_ = W_ih + nrow * DM;
    const float bs = b_ih[rrow] + b_hh[rrow];
    const float bz = b_ih[zrow] + b_hh[zrow];
    const float bh = b_hh[nrow], bi = b_ih[nrow];
#pragma unroll
    for (int w = 0; w < 4; ++w) {
      const int k0 = 8 * q + 2 * w;
      aR0.u[w] = pk(wr[k0], wr[k0 + 1]);
      aZ0.u[w] = pk(wz[k0], wz[k0 + 1]);
      aG0.u[w] = pk(wn[k0], wn[k0 + 1]);
      aR1.u[w] = pk(kv48(wr, ir, bs, 32 + k0), kv48(wr, ir, bs, 33 + k0));
      aZ1.u[w] = pk(kv48(wz, iz, bz, 32 + k0), kv48(wz, iz, bz, 33 + k0));
      aG1.u[w] = pk(kv48(wn, nullptr, bh, 32 + k0), kv48(wn, nullptr, bh, 33 + k0));
      // gi A-frag: x weights at k0..5, b_ih at k6 (only q==0 k-slots nonzero)
      const int kk0 = 2 * w;
      auto gv = [&](int k) -> float { return k < 6 ? in_[k] : (k == 6 ? bi : 0.0f); };
      aGI.u[w] = (q == 0) ? pk(gv(kk0), gv(kk0 + 1)) : 0u;
    }
  }
  F8 aFC0, aFC1;
  if (wid == 0) {
    const bool vr = (c < DM);
    const float* wr = vr ? (fc_w + c * H) : nullptr;
    const float fb = vr ? fc_b[c] : 0.0f;
#pragma unroll
    for (int w = 0; w < 4; ++w) {
      const int k0 = 8 * q + 2 * w;
      aFC0.u[w] = wr ? pk(wr[k0], wr[k0 + 1]) : 0u;
      aFC1.u[w] = pk(kv48(wr, nullptr, fb, 32 + k0), kv48(wr, nullptr, fb, 33 + k0));
    }
  } else {
#pragma unroll
    for (int w = 0; w < 4; ++w) { aFC0.u[w] = 0u; aFC1.u[w] = 0u; }
  }

  // zero both h buffers (h[-1] = 0)
  for (int i = tid; i < 2 * 16 * CSTR; i += 192) ((unsigned*)hbuf)[i] = 0u;

  // x: lanes in quads 0 and 2 hold x for batch bb+c (q2 feeds B1, q0 feeds XB)
  const float* xp = x + (bb + c) * (size_t)(T * DM);
  const bool xl = (q == 0) || (q == 2);
  float2 nx0 = {0, 0}, nx1 = {0, 0}, nx2 = {0, 0};
  if (xl) { const float2* p = (const float2*)xp; nx0 = p[0]; nx1 = p[1]; nx2 = p[2]; }
  unsigned xw0 = pk(nx0.x, nx0.y), xw1 = pk(nx1.x, nx1.y), xw2 = pk(nx2.x, nx2.y);
  if (xl) { const float2* p = (const float2*)(xp + DM); nx0 = p[0]; nx1 = p[1]; nx2 = p[2]; }

  float* yp = y + (bb + c) * (size_t)(T * DM);
  const unsigned c10 = 0x00003C00u;          // f16 pair (1.0, 0.0)
  const f32x4 z4 = {0.0f, 0.0f, 0.0f, 0.0f};
  float hf[4] = {0.0f, 0.0f, 0.0f, 0.0f};    // this wave's h rows 16wid+4q+j, col c

  const int rd0 = c * CSTR + 4 * q;          // chunk0: pairs 4q..4q+3 = k 8q..8q+7
  const int rd1 = c * CSTR + 16 + 4 * q;     // chunk1 (q<2): pairs 16+4q.. = k 32+8q..
  const int wr_ = c * CSTR + 8 * wid + 2 * q; // write: pairs for rows 16wid+4q..+3

  __syncthreads();

#pragma unroll 1
  for (int t = 0; t < T; ++t) {
    const unsigned* hb = &hbuf[t & 1][0];
    unsigned* hn = &hbuf[(t + 1) & 1][0];

    // ---- build B fragments from LDS h + register x ----
    F8 B0, B1, XB;
    {
      const uint4 h0 = *(const uint4*)&hb[rd0];
      B0.u[0] = h0.x; B0.u[1] = h0.y; B0.u[2] = h0.z; B0.u[3] = h0.w;
      uint4 h1 = {0, 0, 0, 0};
      if (q < 2) h1 = *(const uint4*)&hb[rd1];
      B1.u[0] = (q == 2) ? xw0 : ((q == 3) ? 0u : h1.x);
      B1.u[1] = (q == 2) ? xw1 : ((q == 3) ? 0u : h1.y);
      B1.u[2] = (q == 2) ? xw2 : ((q == 3) ? 0u : h1.z);
      B1.u[3] = (q == 2) ? c10 : ((q == 3) ? 0u : h1.w);
      XB.u[0] = (q == 0) ? xw0 : 0u; XB.u[1] = (q == 0) ? xw1 : 0u;
      XB.u[2] = (q == 0) ? xw2 : 0u; XB.u[3] = (q == 0) ? c10 : 0u;
    }

    // ---- FC for y[t-1] (wave0; current frags hold h[t-1]) ----
    if (wid == 0 && t > 0) {
      f32x4 yacc = __builtin_amdgcn_mfma_f32_16x16x32_f16(aFC0.v, B0.v, z4, 0, 0, 0);
      yacc = __builtin_amdgcn_mfma_f32_16x16x32_f16(aFC1.v, B1.v, yacc, 0, 0, 0);
      if (q == 0) {
        float2 s0 = {yacc[0], yacc[1]}, s1 = {yacc[2], yacc[3]};
        *(float2*)(yp + (t - 1) * DM) = s0;
        *(float2*)(yp + (t - 1) * DM + 2) = s1;
      } else if (q == 1) {
        float2 s = {yacc[0], yacc[1]};
        *(float2*)(yp + (t - 1) * DM + 4) = s;
      }
    }

    // ---- this wave's gate tiles: 7 MFMAs ----
    f32x4 aR = __builtin_amdgcn_mfma_f32_16x16x32_f16(aR0.v, B0.v, z4, 0, 0, 0);
    aR = __builtin_amdgcn_mfma_f32_16x16x32_f16(aR1.v, B1.v, aR, 0, 0, 0);
    f32x4 aZ = __builtin_amdgcn_mfma_f32_16x16x32_f16(aZ0.v, B0.v, z4, 0, 0, 0);
    aZ = __builtin_amdgcn_mfma_f32_16x16x32_f16(aZ1.v, B1.v, aZ, 0, 0, 0);
    f32x4 aG = __builtin_amdgcn_mfma_f32_16x16x32_f16(aG0.v, B0.v, z4, 0, 0, 0);
    aG = __builtin_amdgcn_mfma_f32_16x16x32_f16(aG1.v, B1.v, aG, 0, 0, 0);
    f32x4 aI = __builtin_amdgcn_mfma_f32_16x16x32_f16(aGI.v, XB.v, z4, 0, 0, 0);

    // commit x[t+1] (loaded last iter), issue x[t+2]
    xw0 = pk(nx0.x, nx0.y); xw1 = pk(nx1.x, nx1.y); xw2 = pk(nx2.x, nx2.y);
    if (xl) {
      const int tn = (t + 2 < T) ? (t + 2) : (T - 1);
      const float2* p = (const float2*)(xp + tn * DM);
      nx0 = p[0]; nx1 = p[1]; nx2 = p[2];
    }

    // ---- activations + combine (4 sets/lane) ----
#pragma unroll
    for (int j = 0; j < 4; ++j) {
      const float r_ = sigmoid_f(aR[j]);
      const float z_ = sigmoid_f(aZ[j]);
      const float n_ = tanh_f(fmaf(r_, aG[j], aI[j]));
      hf[j] = fmaf(z_, hf[j] - n_, n_);       // n + z*(h-n)
    }
    const unsigned hp0 = pk_rtn(hf[0], hf[1]);
    const unsigned hp1 = pk_rtn(hf[2], hf[3]);
    *(uint2*)&hn[wr_] = (uint2){hp0, hp1};    // ds_write_b64

    bar_lgkm();                               // h[t] visible; vm loads in flight
  }

  // ---- epilogue: y[T-1] from h[T-1] (in hbuf[T&1] = hbuf[0]) ----
  if (wid == 0) {
    const unsigned* hb = &hbuf[T & 1][0];
    F8 B0, B1;
    const uint4 h0 = *(const uint4*)&hb[rd0];
    B0.u[0] = h0.x; B0.u[1] = h0.y; B0.u[2] = h0.z; B0.u[3] = h0.w;
    uint4 h1 = {0, 0, 0, 0};
    if (q < 2) h1 = *(const uint4*)&hb[rd1];
    B1.u[0] = (q == 2) ? xw0 : ((q == 3) ? 0u : h1.x);
    B1.u[1] = (q == 2) ? xw1 : ((q == 3) ? 0u : h1.y);
    B1.u[2] = (q == 2) ? xw2 : ((q == 3) ? 0u : h1.z);
    B1.u[3] = (q == 2) ? c10 : ((q == 3) ? 0u : h1.w);
    f32x4 yacc = __builtin_amdgcn_mfma_f32_16x16x32_f16(aFC0.v, B0.v, z4, 0, 0, 0);
    yacc = __builtin_amdgcn_mfma_f32_16x16x32_f16(aFC1.v, B1.v, yacc, 0, 0, 0);
    if (q == 0) {
      float2 s0 = {yacc[0], yacc[1]}, s1 = {yacc[2], yacc[3]};
      *(float2*)(yp + (T - 1) * DM) = s0;
      *(float2*)(yp + (T - 1) * DM + 2) = s1;
    } else if (q == 1) {
      float2 s = {yacc[0], yacc[1]};
      *(float2*)(yp + (T - 1) * DM + 4) = s;
    }
  }
}

}  // namespace

extern "C" void kernel_launch(void* const* d_in, const int* in_sizes, int n_in,
                              void* d_out, int out_size, void* d_ws, size_t ws_size,
                              hipStream_t stream) {
  const float* x    = (const float*)d_in[0];
  const float* W_ih = (const float*)d_in[1];
  const float* W_hh = (const float*)d_in[2];
  const float* b_ih = (const float*)d_in[3];
  const float* b_hh = (const float*)d_in[4];
  const float* fc_w = (const float*)d_in[5];
  const float* fc_b = (const float*)d_in[6];
  float* y = (float*)d_out;

  constexpr int B = 2048;
  gru_mfma3<<<B / NB, 192, 0, stream>>>(x, W_ih, W_hh, b_ih, b_hh, fc_w, fc_b, y);
}